// Round 2
// baseline (165.482 us; speedup 1.0000x reference)
//
#include <hip/hip_runtime.h>
#include <math.h>

// Problem constants
#define BATCH 4
#define NNODE 10000
#define EDIM  32
#define CDIM  128
#define ODIM  128
#define MTOT  (BATCH * NNODE)   // 40000

__device__ __forceinline__ unsigned short f2bf(float f) {
    unsigned u = __float_as_uint(f);
    u += 0x7fffu + ((u >> 16) & 1u);   // RTNE
    return (unsigned short)(u >> 16);
}

// ---------------------------------------------------------------------------
// Algebra: W = [W1; W2] (rows 0..127 = W1, 128..255 = W2).
//   h[b,n,e] = elu( x[b,n]@(W1-W2) + b  +  x[b,idx_e]@W2 )
// so precompute U = x@(W1-W2)+bias (per node) and T = x@W2 (per node);
// per-edge work collapses to gather+max, and elu moves outside the max
// (monotonic, U constant over e):  out = elu(U + max_e T[idx_e]).
//
// GEMM: rows m in [0,40000), K=128.
//   blockIdx.y == 0:  U[m][n] (fp32 -> ws)    blockIdx.y == 1:  T[m][n] (bf16 -> ws)
// BM=64, BN=128, BK=64 (2 steps), 256 threads, thread tile 4x8.
// As is stored transposed [k][m] with a xor swizzle on 4-float column blocks:
// phys(k,m) = k*64 + (((m>>2) ^ ((k>>2)&15))&15)*4 + (m&3)
// -> staging writes and compute reads both <=2-way conflict (free on gfx950).
// ---------------------------------------------------------------------------
__global__ __launch_bounds__(256, 2) void gemm_ut(
    const float* __restrict__ x,      // [40000,128]
    const float* __restrict__ W,      // [256,128]
    const float* __restrict__ bias,   // [128]
    float* __restrict__ U,            // [40000,128] fp32
    unsigned short* __restrict__ T)   // [40000,128] bf16
{
    __shared__ float As[64 * 64];     // swizzled transposed A tile
    __shared__ float Bs[64 * 128];    // [k][n]

    const int tid = threadIdx.x;
    const int m0  = blockIdx.x * 64;
    const int isT = blockIdx.y;

    const int tm = (tid & 15) * 4;    // 4 rows
    const int tn = (tid >> 4) * 8;    // 8 cols

    float acc[4][8];
    #pragma unroll
    for (int i = 0; i < 4; i++)
        #pragma unroll
        for (int j = 0; j < 8; j++) acc[i][j] = 0.f;

    for (int k0 = 0; k0 < 128; k0 += 64) {
        // ---- stage A (64 rows x 64 k), transposed + swizzled ----
        #pragma unroll
        for (int i = 0; i < 4; i++) {
            int lin = i * 256 + tid;          // float4 index, 0..1023
            int row = lin >> 4;               // 0..63
            int kq  = lin & 15;               // which float4 along k
            float4 v = *(const float4*)&x[(size_t)(m0 + row) * CDIM + k0 + kq * 4];
            int colblock = ((row >> 2) ^ kq) & 15;
            int base = (kq * 4) * 64 + colblock * 4 + (row & 3);
            As[base        ] = v.x;
            As[base + 64   ] = v.y;
            As[base + 128  ] = v.z;
            As[base + 192  ] = v.w;
        }
        // ---- stage B (64 k x 128 n) ----
        #pragma unroll
        for (int i = 0; i < 8; i++) {
            int lin = i * 256 + tid;          // float4 index, 0..2047
            int kk  = lin >> 5;               // 0..63
            int nq  = (lin & 31) * 4;         // 0..124
            int kg  = k0 + kk;
            float4 w2 = *(const float4*)&W[(size_t)(kg + 128) * ODIM + nq];
            float4 v;
            if (!isT) {
                float4 w1 = *(const float4*)&W[(size_t)kg * ODIM + nq];
                v = make_float4(w1.x - w2.x, w1.y - w2.y, w1.z - w2.z, w1.w - w2.w);
            } else {
                v = w2;
            }
            *(float4*)&Bs[kk * 128 + nq] = v;
        }
        __syncthreads();

        // ---- compute ----
        #pragma unroll 8
        for (int kk = 0; kk < 64; kk++) {
            int ab = kk * 64 + ((((tm >> 2) ^ (kk >> 2)) & 15) << 2);
            float4 a  = *(const float4*)&As[ab];
            float4 b0 = *(const float4*)&Bs[kk * 128 + tn];
            float4 b1 = *(const float4*)&Bs[kk * 128 + tn + 4];
            float av[4] = {a.x, a.y, a.z, a.w};
            float bv[8] = {b0.x, b0.y, b0.z, b0.w, b1.x, b1.y, b1.z, b1.w};
            #pragma unroll
            for (int i = 0; i < 4; i++)
                #pragma unroll
                for (int j = 0; j < 8; j++)
                    acc[i][j] = fmaf(av[i], bv[j], acc[i][j]);
        }
        __syncthreads();
    }

    if (!isT) {
        float4 bb0 = *(const float4*)&bias[tn];
        float4 bb1 = *(const float4*)&bias[tn + 4];
        #pragma unroll
        for (int i = 0; i < 4; i++) {
            size_t off = (size_t)(m0 + tm + i) * ODIM + tn;
            float4 o0 = make_float4(acc[i][0] + bb0.x, acc[i][1] + bb0.y,
                                    acc[i][2] + bb0.z, acc[i][3] + bb0.w);
            float4 o1 = make_float4(acc[i][4] + bb1.x, acc[i][5] + bb1.y,
                                    acc[i][6] + bb1.z, acc[i][7] + bb1.w);
            *(float4*)&U[off]     = o0;
            *(float4*)&U[off + 4] = o1;
        }
    } else {
        #pragma unroll
        for (int i = 0; i < 4; i++) {
            size_t off = (size_t)(m0 + tm + i) * ODIM + tn;
            ushort4 h0, h1;
            h0.x = f2bf(acc[i][0]); h0.y = f2bf(acc[i][1]);
            h0.z = f2bf(acc[i][2]); h0.w = f2bf(acc[i][3]);
            h1.x = f2bf(acc[i][4]); h1.y = f2bf(acc[i][5]);
            h1.z = f2bf(acc[i][6]); h1.w = f2bf(acc[i][7]);
            *(ushort4*)&T[off]     = h0;
            *(ushort4*)&T[off + 4] = h1;
        }
    }
}

// ---------------------------------------------------------------------------
// Gather + max + elu. One 64-lane wave per node; 2 outputs/lane (bf16x2 dword
// loads of T). Wave-uniform edge-validity branch. XCD swizzle: blockIdx%8 ->
// batch pair so each XCD's gathers stay in one batch's 2.56MB T slice.
// NOTE: Uin/T/out are all distinct allocations here (no aliasing, no
// restrict lies) -- U and T live in d_ws, out is d_out, written exactly once.
// ---------------------------------------------------------------------------
__global__ __launch_bounds__(256) void gather_max(
    const int* __restrict__ idx,            // [40000,32]
    const float* Uin,                       // [40000,128] fp32 (ws)
    const unsigned short* __restrict__ T,   // [40000,128] bf16 (ws)
    float* out)                             // [40000,128] (d_out)
{
    const int g    = blockIdx.x;            // 0..9999
    const int pair = g & 7;
    const int b    = pair >> 1;             // batch 0..3
    const int wb   = (g >> 3) * 2 + (pair & 1);   // 0..2499 within batch
    const int wave = threadIdx.x >> 6;      // 0..3
    const int lane = threadIdx.x & 63;

    const int nb   = wb * 4 + wave;         // node within batch
    const int node = b * NNODE + nb;        // global row

    __shared__ int sidx[4][EDIM];
    if (threadIdx.x < 4 * EDIM) {
        int w = threadIdx.x >> 5;
        int e = threadIdx.x & 31;
        sidx[w][e] = idx[(size_t)(b * NNODE + wb * 4 + w) * EDIM + e];
    }
    __syncthreads();

    const unsigned short* tb = T + (size_t)b * NNODE * ODIM;
    const int o2 = lane * 2;

    float m0 = -INFINITY, m1 = -INFINITY;
    bool any = false;
    #pragma unroll
    for (int e = 0; e < EDIM; e++) {
        int j = sidx[wave][e];              // wave-uniform
        if (j >= 0) {
            any = true;
            unsigned v = *(const unsigned*)(tb + (size_t)j * ODIM + o2);
            float f0 = __uint_as_float(v << 16);
            float f1 = __uint_as_float(v & 0xffff0000u);
            m0 = fmaxf(m0, f0);
            m1 = fmaxf(m1, f1);
        }
    }

    float2 uv = *(const float2*)&Uin[(size_t)node * ODIM + o2];
    float r0, r1;
    if (any) {
        float s0 = uv.x + m0;
        float s1 = uv.y + m1;
        r0 = s0 > 0.f ? s0 : __expf(s0) - 1.f;
        r1 = s1 > 0.f ? s1 : __expf(s1) - 1.f;
    } else {
        r0 = -INFINITY;
        r1 = -INFINITY;
    }
    *(float2*)&out[(size_t)node * ODIM + o2] = make_float2(r0, r1);
}

extern "C" void kernel_launch(void* const* d_in, const int* in_sizes, int n_in,
                              void* d_out, int out_size, void* d_ws, size_t ws_size,
                              hipStream_t stream) {
    const float* x    = (const float*)d_in[0];
    const int*   idx  = (const int*)d_in[1];
    const float* W    = (const float*)d_in[2];
    const float* bias = (const float*)d_in[3];
    float* out        = (float*)d_out;

    // ws layout: T bf16 [40000*128] = 10.24 MB, then U fp32 [40000*128] = 20.48 MB
    const size_t tBytes = (size_t)MTOT * ODIM * sizeof(unsigned short);
    const size_t uBytes = (size_t)MTOT * ODIM * sizeof(float);
    unsigned short* T = (unsigned short*)d_ws;
    float* U;
    if (ws_size >= tBytes + uBytes) {
        U = (float*)((char*)d_ws + tBytes);       // preferred: U in ws, no aliasing
    } else {
        U = out;                                  // fallback: U staged in d_out
    }

    gemm_ut<<<dim3(MTOT / 64, 2), 256, 0, stream>>>(x, W, bias, U, T);
    gather_max<<<(MTOT / 4), 256, 0, stream>>>(idx, U, T, out);
}

// Round 3
// 136.040 us; speedup vs baseline: 1.2164x; 1.2164x over previous
//
#include <hip/hip_runtime.h>
#include <math.h>

// Problem constants
#define BATCH 4
#define NNODE 10000
#define EDIM  32
#define CDIM  128
#define ODIM  128
#define MTOT  (BATCH * NNODE)   // 40000

__device__ __forceinline__ unsigned short f2bf(float f) {
    unsigned u = __float_as_uint(f);
    u += 0x7fffu + ((u >> 16) & 1u);   // RTNE
    return (unsigned short)(u >> 16);
}

// ---------------------------------------------------------------------------
// Algebra: W = [W1; W2].  h[b,n,e] = elu( x[b,n]@(W1-W2)+b + x[b,idx_e]@W2 ),
// elu monotonic -> out = elu(U + max_e T[idx_e]) with U,T per-node GEMMs.
//
// Fused GEMM: ONE pass over x computes both U (fp32) and T (bf16).
// BM=64, BN=128, BK=64 (2 steps), 256 threads, 4x8 thread tile, dual acc.
// As transposed [k][m] with xor swizzle (staging + reads <=2-way conflict).
// LDS: As 16K + Bd 32K + B2 32K = 80 KB -> 2 blocks/CU.
// ---------------------------------------------------------------------------
__global__ __launch_bounds__(256, 2) void gemm_fused(
    const float* __restrict__ x,      // [40000,128]
    const float* __restrict__ W,      // [256,128]
    const float* __restrict__ bias,   // [128]
    float* __restrict__ U,            // [40000,128] fp32
    unsigned short* __restrict__ T)   // [40000,128] bf16
{
    __shared__ float As[64 * 64];     // swizzled transposed A tile
    __shared__ float Bd[64 * 128];    // W1 - W2
    __shared__ float B2[64 * 128];    // W2

    const int tid = threadIdx.x;
    const int m0  = blockIdx.x * 64;

    const int tm = (tid & 15) * 4;    // 4 rows
    const int tn = (tid >> 4) * 8;    // 8 cols

    float accU[4][8], accT[4][8];
    #pragma unroll
    for (int i = 0; i < 4; i++)
        #pragma unroll
        for (int j = 0; j < 8; j++) { accU[i][j] = 0.f; accT[i][j] = 0.f; }

    for (int k0 = 0; k0 < 128; k0 += 64) {
        // ---- stage A (64 rows x 64 k), transposed + swizzled ----
        #pragma unroll
        for (int i = 0; i < 4; i++) {
            int lin = i * 256 + tid;          // float4 index, 0..1023
            int row = lin >> 4;               // 0..63
            int kq  = lin & 15;               // which float4 along k
            float4 v = *(const float4*)&x[(size_t)(m0 + row) * CDIM + k0 + kq * 4];
            int colblock = ((row >> 2) ^ kq) & 15;
            int base = (kq * 4) * 64 + colblock * 4 + (row & 3);
            As[base      ] = v.x;
            As[base + 64 ] = v.y;
            As[base + 128] = v.z;
            As[base + 192] = v.w;
        }
        // ---- stage B tiles: Bd = W1-W2, B2 = W2 ----
        #pragma unroll
        for (int i = 0; i < 8; i++) {
            int lin = i * 256 + tid;          // float4 index, 0..2047
            int kk  = lin >> 5;               // 0..63
            int nq  = (lin & 31) * 4;         // 0..124
            int kg  = k0 + kk;
            float4 w1 = *(const float4*)&W[(size_t)kg * ODIM + nq];
            float4 w2 = *(const float4*)&W[(size_t)(kg + 128) * ODIM + nq];
            *(float4*)&Bd[kk * 128 + nq] =
                make_float4(w1.x - w2.x, w1.y - w2.y, w1.z - w2.z, w1.w - w2.w);
            *(float4*)&B2[kk * 128 + nq] = w2;
        }
        __syncthreads();

        // ---- compute: 64 FMAs/kk (32 U + 32 T) ----
        #pragma unroll 4
        for (int kk = 0; kk < 64; kk++) {
            int ab = kk * 64 + ((((tm >> 2) ^ (kk >> 2)) & 15) << 2);
            float4 a  = *(const float4*)&As[ab];
            float4 d0 = *(const float4*)&Bd[kk * 128 + tn];
            float4 d1 = *(const float4*)&Bd[kk * 128 + tn + 4];
            float4 c0 = *(const float4*)&B2[kk * 128 + tn];
            float4 c1 = *(const float4*)&B2[kk * 128 + tn + 4];
            float av[4] = {a.x, a.y, a.z, a.w};
            float dv[8] = {d0.x, d0.y, d0.z, d0.w, d1.x, d1.y, d1.z, d1.w};
            float cv[8] = {c0.x, c0.y, c0.z, c0.w, c1.x, c1.y, c1.z, c1.w};
            #pragma unroll
            for (int i = 0; i < 4; i++)
                #pragma unroll
                for (int j = 0; j < 8; j++) {
                    accU[i][j] = fmaf(av[i], dv[j], accU[i][j]);
                    accT[i][j] = fmaf(av[i], cv[j], accT[i][j]);
                }
        }
        __syncthreads();
    }

    float4 bb0 = *(const float4*)&bias[tn];
    float4 bb1 = *(const float4*)&bias[tn + 4];
    #pragma unroll
    for (int i = 0; i < 4; i++) {
        size_t off = (size_t)(m0 + tm + i) * ODIM + tn;
        float4 o0 = make_float4(accU[i][0] + bb0.x, accU[i][1] + bb0.y,
                                accU[i][2] + bb0.z, accU[i][3] + bb0.w);
        float4 o1 = make_float4(accU[i][4] + bb1.x, accU[i][5] + bb1.y,
                                accU[i][6] + bb1.z, accU[i][7] + bb1.w);
        *(float4*)&U[off]     = o0;
        *(float4*)&U[off + 4] = o1;
        ushort4 h0, h1;
        h0.x = f2bf(accT[i][0]); h0.y = f2bf(accT[i][1]);
        h0.z = f2bf(accT[i][2]); h0.w = f2bf(accT[i][3]);
        h1.x = f2bf(accT[i][4]); h1.y = f2bf(accT[i][5]);
        h1.z = f2bf(accT[i][6]); h1.w = f2bf(accT[i][7]);
        *(ushort4*)&T[off]     = h0;
        *(ushort4*)&T[off + 4] = h1;
    }
}

// ---------------------------------------------------------------------------
// Gather + max + elu, latency-optimized.
// Block = 256 threads = 8 nodes; each half-wave (32 lanes) owns one node,
// each lane covers 4 outputs via one uint2 (bf16x4) load -> vmem instrs
// halved vs dword/lane. Valid edge indices are COMPACTED in LDS (ballot +
// prefix popcount), padded to a multiple of 8 with a duplicate of entry 0
// (max is idempotent) -> branch-free inner loop with 8 loads in flight.
// XCD swizzle keeps each XCD's gathers inside one batch's 2.56MB T slice.
// ---------------------------------------------------------------------------
__global__ __launch_bounds__(256) void gather_max(
    const int* __restrict__ idx,            // [40000,32]
    const float* __restrict__ Uin,          // [40000,128] fp32 (ws)
    const unsigned short* __restrict__ T,   // [40000,128] bf16 (ws)
    float* __restrict__ out)                // [40000,128] (d_out)
{
    __shared__ int scomp[8][EDIM];
    __shared__ int scnt[8];

    const int g    = blockIdx.x;            // 0..4999
    const int b    = (g & 7) >> 1;          // batch 0..3
    const int wb   = (g >> 3) * 2 + (g & 1);// 0..1249 within batch
    const int nb0  = wb * 8;                // first node of this block
    const int tid  = threadIdx.x;
    const int lane = tid & 63;
    const int wv   = tid >> 6;

    // ---- compact valid indices per node ----
    {
        int n = tid >> 5;                   // 0..7 local node
        int e = tid & 31;
        int j = idx[(size_t)(b * NNODE + nb0 + n) * EDIM + e];
        bool valid = j >= 0;
        unsigned long long ball = __ballot(valid);
        unsigned long long grp  = (lane >= 32) ? 0xFFFFFFFF00000000ull
                                               : 0x00000000FFFFFFFFull;
        unsigned long long below = (lane == 0) ? 0ull : (~0ull >> (64 - lane));
        int pos = __popcll(ball & grp & below);
        if (valid) scomp[n][pos] = j;
        if (e == 0) scnt[n] = __popcll(ball & grp);
    }
    __syncthreads();
    // ---- pad compacted list to multiple of 8 with a valid duplicate ----
    {
        int n = tid >> 5;
        int e = tid & 31;
        int cnt = scnt[n];
        int Kp  = (cnt + 7) & ~7;
        if (cnt > 0 && e >= cnt && e < Kp) scomp[n][e] = scomp[n][0];
    }
    __syncthreads();

    const int half = lane >> 5;             // which node of the wave's pair
    const int myn  = wv * 2 + half;         // 0..7
    const int hl   = lane & 31;
    const int node = b * NNODE + nb0 + myn;
    const unsigned short* tb = T + (size_t)b * NNODE * ODIM;
    const int o4 = hl * 4;                  // bf16 element offset (8B aligned)

    const int cnt = scnt[myn];
    const int Kp  = (cnt + 7) & ~7;

    float m0 = -INFINITY, m1 = -INFINITY, m2 = -INFINITY, m3 = -INFINITY;
    for (int e0 = 0; e0 < Kp; e0 += 8) {
        uint2 v[8];
        #pragma unroll
        for (int q = 0; q < 8; q++) {
            int j = scomp[myn][e0 + q];
            v[q] = *(const uint2*)(tb + (size_t)j * ODIM + o4);
        }
        #pragma unroll
        for (int q = 0; q < 8; q++) {
            m0 = fmaxf(m0, __uint_as_float(v[q].x << 16));
            m1 = fmaxf(m1, __uint_as_float(v[q].x & 0xffff0000u));
            m2 = fmaxf(m2, __uint_as_float(v[q].y << 16));
            m3 = fmaxf(m3, __uint_as_float(v[q].y & 0xffff0000u));
        }
    }

    float4 uv = *(const float4*)&Uin[(size_t)node * ODIM + o4];
    float4 r;
    if (cnt > 0) {
        float s0 = uv.x + m0, s1 = uv.y + m1;
        float s2 = uv.z + m2, s3 = uv.w + m3;
        r.x = s0 > 0.f ? s0 : __expf(s0) - 1.f;
        r.y = s1 > 0.f ? s1 : __expf(s1) - 1.f;
        r.z = s2 > 0.f ? s2 : __expf(s2) - 1.f;
        r.w = s3 > 0.f ? s3 : __expf(s3) - 1.f;
    } else {
        r = make_float4(-INFINITY, -INFINITY, -INFINITY, -INFINITY);
    }
    *(float4*)&out[(size_t)node * ODIM + o4] = r;
}

extern "C" void kernel_launch(void* const* d_in, const int* in_sizes, int n_in,
                              void* d_out, int out_size, void* d_ws, size_t ws_size,
                              hipStream_t stream) {
    const float* x    = (const float*)d_in[0];
    const int*   idx  = (const int*)d_in[1];
    const float* W    = (const float*)d_in[2];
    const float* bias = (const float*)d_in[3];
    float* out        = (float*)d_out;

    // ws layout: T bf16 [40000*128] = 10.24 MB, then U fp32 [40000*128] = 20.48 MB
    const size_t tBytes = (size_t)MTOT * ODIM * sizeof(unsigned short);
    const size_t uBytes = (size_t)MTOT * ODIM * sizeof(float);
    unsigned short* T = (unsigned short*)d_ws;
    float* U = (ws_size >= tBytes + uBytes) ? (float*)((char*)d_ws + tBytes)
                                            : out;   // fallback: stage U in d_out

    gemm_fused<<<MTOT / 64, 256, 0, stream>>>(x, W, bias, U, T);
    gather_max<<<MTOT / 8, 256, 0, stream>>>(idx, U, T, out);
}

// Round 4
// 128.851 us; speedup vs baseline: 1.2843x; 1.0558x over previous
//
#include <hip/hip_runtime.h>
#include <math.h>

// Problem constants
#define BATCH 4
#define NNODE 10000
#define EDIM  32
#define CDIM  128
#define ODIM  128
#define MTOT  (BATCH * NNODE)   // 40000

typedef __attribute__((ext_vector_type(8))) short bf16x8;   // MFMA A/B frag (4 VGPRs)
typedef __attribute__((ext_vector_type(4))) float f32x4;    // MFMA C/D frag

__device__ __forceinline__ unsigned short f2bf(float f) {
    unsigned u = __float_as_uint(f);
    u += 0x7fffu + ((u >> 16) & 1u);   // RTNE
    return (unsigned short)(u >> 16);
}

// ---------------------------------------------------------------------------
// prep_w: Bcat[n][k] bf16, n-major (transposed) so GEMM B-fragments are
// contiguous dwordx4 loads. n<128: W1[k][n]-W2[k][n]; n>=128: W2[k][n-128].
// 64 KB output, stays hot in L2 for the GEMM.
// ---------------------------------------------------------------------------
__global__ __launch_bounds__(256) void prep_w(
    const float* __restrict__ W, unsigned short* __restrict__ Bcat)
{
    int gid = blockIdx.x * 256 + threadIdx.x;   // 32768 threads, 1 elem each
    int n = gid >> 7;          // 0..255
    int k = gid & 127;         // 0..127
    float v;
    if (n < 128) v = W[(size_t)k * ODIM + n] - W[(size_t)(k + 128) * ODIM + n];
    else         v = W[(size_t)(k + 128) * ODIM + (n - 128)];
    Bcat[(size_t)n * CDIM + k] = f2bf(v);
}

// ---------------------------------------------------------------------------
// MFMA GEMM: A = x (fp32 -> bf16 in-register), B = Bcat (bf16, [n][k]).
// One block = 64 rows x 256 cols (cols 0..127 -> U fp32 +bias, 128..255 -> T
// bf16). 4 waves, each wave owns a 64-col quarter: 4x4 tiles of 16x16x32,
// K = 128 = 4 ksteps. NO LDS: A frags load straight from x (4 waves share the
// same 64-row strip -> L1 reuse), B frags straight from Bcat (L2-hot).
// 16x16x32 layouts (m89/m120-verified): A[m=lane&15][k=quad*8+j],
// B[k=quad*8+j][n=lane&15], C/D col=lane&15, row=quad*4+reg.
// ---------------------------------------------------------------------------
__global__ __launch_bounds__(256) void gemm_mfma(
    const float* __restrict__ x,            // [40000,128]
    const unsigned short* __restrict__ Bcat,// [256,128] bf16
    const float* __restrict__ bias,         // [128]
    float* __restrict__ U,                  // [40000,128] fp32
    unsigned short* __restrict__ T)         // [40000,128] bf16
{
    const int m0   = blockIdx.x * 64;
    const int wv   = threadIdx.x >> 6;      // 0..3 -> col quarter
    const int lane = threadIdx.x & 63;
    const int l16  = lane & 15;
    const int quad = lane >> 4;
    const int nq   = wv * 64;               // this wave's first col (0..192)

    f32x4 acc[4][4];
    #pragma unroll
    for (int i = 0; i < 4; i++)
        #pragma unroll
        for (int j = 0; j < 4; j++) acc[i][j] = (f32x4){0.f, 0.f, 0.f, 0.f};

    const float* xb = x + (size_t)m0 * CDIM;

    #pragma unroll
    for (int ks = 0; ks < 4; ks++) {
        const int kb = ks * 32 + quad * 8;  // lane's 8-k run within this kstep

        bf16x8 bfr[4];
        #pragma unroll
        for (int ct = 0; ct < 4; ct++)      // B frags: contiguous 16B loads
            bfr[ct] = *(const bf16x8*)(Bcat + (size_t)(nq + ct * 16 + l16) * CDIM + kb);

        bf16x8 afr[4];
        #pragma unroll
        for (int rt = 0; rt < 4; rt++) {    // A frags: 8 fp32 -> bf16
            const float* ap = xb + (size_t)(rt * 16 + l16) * CDIM + kb;
            float4 a0 = *(const float4*)ap;
            float4 a1 = *(const float4*)(ap + 4);
            bf16x8 v;
            v[0] = (short)f2bf(a0.x); v[1] = (short)f2bf(a0.y);
            v[2] = (short)f2bf(a0.z); v[3] = (short)f2bf(a0.w);
            v[4] = (short)f2bf(a1.x); v[5] = (short)f2bf(a1.y);
            v[6] = (short)f2bf(a1.z); v[7] = (short)f2bf(a1.w);
            afr[rt] = v;
        }

        #pragma unroll
        for (int rt = 0; rt < 4; rt++)
            #pragma unroll
            for (int ct = 0; ct < 4; ct++)
                acc[rt][ct] = __builtin_amdgcn_mfma_f32_16x16x32_bf16(
                    afr[rt], bfr[ct], acc[rt][ct], 0, 0, 0);
    }

    // Epilogue. Wave-uniform split: waves 0,1 -> U (fp32 + bias), 2,3 -> T (bf16).
    if (wv < 2) {
        #pragma unroll
        for (int ct = 0; ct < 4; ct++) {
            int n = nq + ct * 16 + l16;
            float bb = bias[n];
            #pragma unroll
            for (int rt = 0; rt < 4; rt++) {
                int row = m0 + rt * 16 + quad * 4;
                #pragma unroll
                for (int r = 0; r < 4; r++)
                    U[(size_t)(row + r) * ODIM + n] = acc[rt][ct][r] + bb;
            }
        }
    } else {
        #pragma unroll
        for (int ct = 0; ct < 4; ct++) {
            int n = nq - 128 + ct * 16 + l16;
            #pragma unroll
            for (int rt = 0; rt < 4; rt++) {
                int row = m0 + rt * 16 + quad * 4;
                #pragma unroll
                for (int r = 0; r < 4; r++)
                    T[(size_t)(row + r) * ODIM + n] = f2bf(acc[rt][ct][r]);
            }
        }
    }
}

// ---------------------------------------------------------------------------
// Gather + max + elu. Wave-per-node (R2 structure, proven correct), but
// branch-free with ALL 32 edge loads in flight: clamp j<0 -> 0, load, then
// mask invalid edges during the fmax pass (wave-uniform if). One dword
// (bf16x2) per lane per edge = full 256B row per instruction.
// XCD swizzle: blockIdx%8 -> batch pair, keeps each XCD's gathers in one
// batch's 2.56MB T slice (fits 4MB per-XCD L2).
// ---------------------------------------------------------------------------
__global__ __launch_bounds__(256) void gather_max(
    const int* __restrict__ idx,            // [40000,32]
    const float* Uin,                       // [40000,128] fp32 (ws)
    const unsigned short* __restrict__ T,   // [40000,128] bf16 (ws)
    float* out)                             // [40000,128] (d_out)
{
    const int g    = blockIdx.x;            // 0..9999
    const int b    = (g & 7) >> 1;          // batch 0..3
    const int wb   = (g >> 3) * 2 + (g & 1);// 0..2499 within batch
    const int wave = threadIdx.x >> 6;      // 0..3
    const int lane = threadIdx.x & 63;
    const int node = b * NNODE + wb * 4 + wave;

    __shared__ int sidx[4][EDIM];
    if (threadIdx.x < 4 * EDIM) {
        int w = threadIdx.x >> 5;
        int e = threadIdx.x & 31;
        sidx[w][e] = idx[(size_t)(b * NNODE + wb * 4 + w) * EDIM + e];
    }
    __syncthreads();

    const unsigned short* tb = T + (size_t)b * NNODE * ODIM;
    const int o2 = lane * 2;

    int      jv[EDIM];
    unsigned vv[EDIM];
    #pragma unroll
    for (int e = 0; e < EDIM; e++) {        // 32 independent loads in flight
        int j = sidx[wave][e];              // wave-uniform (broadcast read)
        jv[e] = j;
        int jc = j < 0 ? 0 : j;
        vv[e] = *(const unsigned*)(tb + (size_t)jc * ODIM + o2);
    }

    float m0 = -INFINITY, m1 = -INFINITY;
    bool any = false;
    #pragma unroll
    for (int e = 0; e < EDIM; e++) {
        if (jv[e] >= 0) {                   // wave-uniform branch
            any = true;
            m0 = fmaxf(m0, __uint_as_float(vv[e] << 16));
            m1 = fmaxf(m1, __uint_as_float(vv[e] & 0xffff0000u));
        }
    }

    float2 uv = *(const float2*)&Uin[(size_t)node * ODIM + o2];
    float r0, r1;
    if (any) {
        float s0 = uv.x + m0;
        float s1 = uv.y + m1;
        r0 = s0 > 0.f ? s0 : __expf(s0) - 1.f;
        r1 = s1 > 0.f ? s1 : __expf(s1) - 1.f;
    } else {
        r0 = -INFINITY;
        r1 = -INFINITY;
    }
    *(float2*)&out[(size_t)node * ODIM + o2] = make_float2(r0, r1);
}

extern "C" void kernel_launch(void* const* d_in, const int* in_sizes, int n_in,
                              void* d_out, int out_size, void* d_ws, size_t ws_size,
                              hipStream_t stream) {
    const float* x    = (const float*)d_in[0];
    const int*   idx  = (const int*)d_in[1];
    const float* W    = (const float*)d_in[2];
    const float* bias = (const float*)d_in[3];
    float* out        = (float*)d_out;

    // ws layout: T bf16 10.24MB | U fp32 20.48MB | Bcat bf16 64KB
    const size_t tBytes = (size_t)MTOT * ODIM * sizeof(unsigned short);
    const size_t uBytes = (size_t)MTOT * ODIM * sizeof(float);
    unsigned short* T = (unsigned short*)d_ws;
    float* U;
    unsigned short* Bcat;
    if (ws_size >= tBytes + uBytes + 256 * CDIM * sizeof(unsigned short)) {
        U    = (float*)((char*)d_ws + tBytes);
        Bcat = (unsigned short*)((char*)d_ws + tBytes + uBytes);
    } else {
        U    = out;                               // fallback: stage U in d_out
        Bcat = (unsigned short*)((char*)d_ws + tBytes);
    }

    prep_w   <<<128,       256, 0, stream>>>(W, Bcat);
    gemm_mfma<<<MTOT / 64, 256, 0, stream>>>(x, Bcat, bias, U, T);
    gather_max<<<MTOT / 4, 256, 0, stream>>>(idx, U, T, out);
}

// Round 5
// 110.418 us; speedup vs baseline: 1.4987x; 1.1669x over previous
//
#include <hip/hip_runtime.h>
#include <math.h>

// Problem constants
#define BATCH 4
#define NNODE 10000
#define EDIM  32
#define CDIM  128
#define ODIM  128
#define MTOT  (BATCH * NNODE)   // 40000

typedef __attribute__((ext_vector_type(8))) short bf16x8;   // MFMA A/B frag (4 VGPRs)
typedef __attribute__((ext_vector_type(4))) float f32x4;    // MFMA C/D frag

__device__ __forceinline__ unsigned short f2bf(float f) {
    unsigned u = __float_as_uint(f);
    u += 0x7fffu + ((u >> 16) & 1u);   // RTNE
    return (unsigned short)(u >> 16);
}

// ---------------------------------------------------------------------------
// prep_w: Bcat[n][k] bf16, n-major so GEMM B-fragments are contiguous 16B
// loads. n<128: W1[k][n]-W2[k][n]; n>=128: W2[k][n-128]. 64KB, L1/L2-hot.
// Also fills the sentinel T row (row 40000) with -inf bf16: invalid edges
// gather from it, making the gather inner loop branch- and mask-free.
// ---------------------------------------------------------------------------
__global__ __launch_bounds__(256) void prep_w(
    const float* __restrict__ W, unsigned short* __restrict__ Bcat,
    unsigned short* __restrict__ Tsent)
{
    int gid = blockIdx.x * 256 + threadIdx.x;   // 32768 threads
    int n = gid >> 7;          // 0..255
    int k = gid & 127;         // 0..127
    float v;
    if (n < 128) v = W[(size_t)k * ODIM + n] - W[(size_t)(k + 128) * ODIM + n];
    else         v = W[(size_t)(k + 128) * ODIM + (n - 128)];
    Bcat[(size_t)n * CDIM + k] = f2bf(v);
    if (gid < ODIM) Tsent[gid] = 0xFF80;        // -inf bf16
}

// ---------------------------------------------------------------------------
// MFMA GEMM, LDS-staged (canonical §5 structure).
// Block = 64 rows x 256 cols (cols 0..127 -> U fp32+bias, 128..255 -> T bf16),
// 4 waves, each wave a 64-col quarter: 4x4 tiles of 16x16x32, K=128.
// A: x fp32 loaded coalesced (float4), converted to bf16 in staging, stored
// to LDS with kblock-XOR swizzle phys_kblk = kblk ^ (row&15) so both staging
// writes and ds_read_b128 fragment reads are <=2-way (free). B: direct 16B
// loads from L1-hot Bcat. 16KB LDS, single stage, 2 barriers.
// Layouts (R4-verified): A[m=lane&15][k=quad*8+j], B[k=quad*8+j][n=lane&15],
// C/D col=lane&15, row=quad*4+reg.
// ---------------------------------------------------------------------------
__global__ __launch_bounds__(256) void gemm_mfma(
    const float* __restrict__ x,            // [40000,128]
    const unsigned short* __restrict__ Bcat,// [256,128] bf16
    const float* __restrict__ bias,         // [128]
    float* __restrict__ U,                  // [40000,128] fp32
    unsigned short* __restrict__ T)         // [40001,128] bf16
{
    __shared__ unsigned short As[64 * 128]; // 16KB, swizzled [row][k]

    const int tid  = threadIdx.x;
    const int m0   = blockIdx.x * 64;
    const int wv   = tid >> 6;
    const int lane = tid & 63;
    const int l16  = lane & 15;
    const int quad = lane >> 4;
    const int nq   = wv * 64;

    // ---- stage + convert: 64 rows x 128 k, coalesced float4 reads ----
    #pragma unroll
    for (int i = 0; i < 8; i++) {
        int lin = i * 256 + tid;            // float4 index, 0..2047
        int row = lin >> 5;                 // 0..63
        int f4  = lin & 31;                 // float4 within row
        float4 v = *(const float4*)&x[(size_t)(m0 + row) * CDIM + f4 * 4];
        ushort4 h;
        h.x = f2bf(v.x); h.y = f2bf(v.y); h.z = f2bf(v.z); h.w = f2bf(v.w);
        int kblk = f4 >> 1, half = f4 & 1;
        *(ushort4*)((char*)As + row * 256 + (((kblk ^ (row & 15)) << 4) + half * 8)) = h;
    }
    __syncthreads();

    f32x4 acc[4][4];
    #pragma unroll
    for (int i = 0; i < 4; i++)
        #pragma unroll
        for (int j = 0; j < 4; j++) acc[i][j] = (f32x4){0.f, 0.f, 0.f, 0.f};

    #pragma unroll
    for (int ks = 0; ks < 4; ks++) {
        const int kb = ks * 32 + quad * 8;

        bf16x8 bfr[4];
        #pragma unroll
        for (int ct = 0; ct < 4; ct++)
            bfr[ct] = *(const bf16x8*)(Bcat + (size_t)(nq + ct * 16 + l16) * CDIM + kb);

        bf16x8 afr[4];
        #pragma unroll
        for (int rt = 0; rt < 4; rt++) {
            int row  = rt * 16 + l16;
            int kblk = ks * 4 + quad;
            afr[rt] = *(const bf16x8*)((char*)As + row * 256 + ((kblk ^ l16) << 4));
        }

        #pragma unroll
        for (int rt = 0; rt < 4; rt++)
            #pragma unroll
            for (int ct = 0; ct < 4; ct++)
                acc[rt][ct] = __builtin_amdgcn_mfma_f32_16x16x32_bf16(
                    afr[rt], bfr[ct], acc[rt][ct], 0, 0, 0);
    }

    // Epilogue (R4-verified): waves 0,1 -> U fp32+bias, waves 2,3 -> T bf16.
    if (wv < 2) {
        #pragma unroll
        for (int ct = 0; ct < 4; ct++) {
            int n = nq + ct * 16 + l16;
            float bb = bias[n];
            #pragma unroll
            for (int rt = 0; rt < 4; rt++) {
                int row = m0 + rt * 16 + quad * 4;
                #pragma unroll
                for (int r = 0; r < 4; r++)
                    U[(size_t)(row + r) * ODIM + n] = acc[rt][ct][r] + bb;
            }
        }
    } else {
        #pragma unroll
        for (int ct = 0; ct < 4; ct++) {
            int n = nq - 128 + ct * 16 + l16;
            #pragma unroll
            for (int rt = 0; rt < 4; rt++) {
                int row = m0 + rt * 16 + quad * 4;
                #pragma unroll
                for (int r = 0; r < 4; r++)
                    T[(size_t)(row + r) * ODIM + n] = f2bf(acc[rt][ct][r]);
            }
        }
    }
}

// ---------------------------------------------------------------------------
// Gather + max + elu. Quarter-wave (16 lanes) per node, uint4 = bf16x8 per
// lane -> one 1KB load instr covers 4 nodes' rows per edge. Invalid indices
// were rewritten at staging to the -inf sentinel row -> inner loop is a pure
// branch-free gather-max; "any valid" falls out as m[0] > -inf. 8 loads
// batched in flight. XCD swizzle b = g&3: with round-robin block->XCD
// dispatch each XCD touches only one batch's 2.56MB T slice (< 4MB L2).
// ---------------------------------------------------------------------------
__global__ __launch_bounds__(256) void gather_max(
    const int* __restrict__ idx,            // [40000,32]
    const float* Uin,                       // [40000,128] fp32 (ws)
    const unsigned short* __restrict__ T,   // [40001,128] bf16 (ws)
    float* out)                             // [40000,128] (d_out)
{
    __shared__ int sidx[16][EDIM];

    const int g   = blockIdx.x;             // 0..2499
    const int b   = g & 3;                  // batch
    const int nb0 = (g >> 2) * 16;          // first node (0..9984)
    const int tid = threadIdx.x;
    const int sent = NNODE * (BATCH - b);   // sentinel row rel. to tb

    #pragma unroll
    for (int i = 0; i < 2; i++) {
        int lin = i * 256 + tid;            // 0..511
        int n = lin >> 5, e = lin & 31;
        int j = idx[(size_t)(b * NNODE + nb0 + n) * EDIM + e];
        sidx[n][e] = (j < 0) ? sent : j;
    }
    __syncthreads();

    const int wv   = tid >> 6;
    const int lane = tid & 63;
    const int q4   = lane >> 4;
    const int l16  = lane & 15;
    const int myn  = wv * 4 + q4;           // 0..15
    const int node = b * NNODE + nb0 + myn;
    const unsigned short* tb = T + (size_t)b * NNODE * ODIM;
    const int o8 = l16 * 8;                 // bf16 col offset (16B aligned)

    float m[8];
    #pragma unroll
    for (int i = 0; i < 8; i++) m[i] = -INFINITY;

    #pragma unroll
    for (int e0 = 0; e0 < EDIM; e0 += 8) {
        uint4 v[8];
        #pragma unroll
        for (int q = 0; q < 8; q++) {       // 8 gathers in flight
            int j = sidx[myn][e0 + q];
            v[q] = *(const uint4*)(tb + (size_t)j * ODIM + o8);
        }
        #pragma unroll
        for (int q = 0; q < 8; q++) {
            m[0] = fmaxf(m[0], __uint_as_float(v[q].x << 16));
            m[1] = fmaxf(m[1], __uint_as_float(v[q].x & 0xffff0000u));
            m[2] = fmaxf(m[2], __uint_as_float(v[q].y << 16));
            m[3] = fmaxf(m[3], __uint_as_float(v[q].y & 0xffff0000u));
            m[4] = fmaxf(m[4], __uint_as_float(v[q].z << 16));
            m[5] = fmaxf(m[5], __uint_as_float(v[q].z & 0xffff0000u));
            m[6] = fmaxf(m[6], __uint_as_float(v[q].w << 16));
            m[7] = fmaxf(m[7], __uint_as_float(v[q].w & 0xffff0000u));
        }
    }

    const bool any = m[0] > -INFINITY;      // all-invalid => every m[i] = -inf
    float4 u0 = *(const float4*)&Uin[(size_t)node * ODIM + o8];
    float4 u1 = *(const float4*)&Uin[(size_t)node * ODIM + o8 + 4];
    float uu[8] = {u0.x, u0.y, u0.z, u0.w, u1.x, u1.y, u1.z, u1.w};
    float r[8];
    #pragma unroll
    for (int i = 0; i < 8; i++) {
        float s = uu[i] + m[i];
        r[i] = any ? (s > 0.f ? s : __expf(s) - 1.f) : -INFINITY;
    }
    float4 w0 = make_float4(r[0], r[1], r[2], r[3]);
    float4 w1 = make_float4(r[4], r[5], r[6], r[7]);
    *(float4*)&out[(size_t)node * ODIM + o8]     = w0;
    *(float4*)&out[(size_t)node * ODIM + o8 + 4] = w1;
}

extern "C" void kernel_launch(void* const* d_in, const int* in_sizes, int n_in,
                              void* d_out, int out_size, void* d_ws, size_t ws_size,
                              hipStream_t stream) {
    const float* x    = (const float*)d_in[0];
    const int*   idx  = (const int*)d_in[1];
    const float* W    = (const float*)d_in[2];
    const float* bias = (const float*)d_in[3];
    float* out        = (float*)d_out;

    // ws layout: T bf16 [(40000+1)*128] | U fp32 [40000*128] | Bcat bf16 [256*128]
    const size_t tBytes = (size_t)(MTOT + 1) * ODIM * sizeof(unsigned short); // 16B-mult
    const size_t uBytes = (size_t)MTOT * ODIM * sizeof(float);
    const size_t bBytes = (size_t)256 * CDIM * sizeof(unsigned short);
    unsigned short* T = (unsigned short*)d_ws;
    float* U;
    unsigned short* Bcat;
    if (ws_size >= tBytes + uBytes + bBytes) {
        U    = (float*)((char*)d_ws + tBytes);
        Bcat = (unsigned short*)((char*)d_ws + tBytes + uBytes);
    } else {
        U    = out;                               // fallback: stage U in d_out
        Bcat = (unsigned short*)((char*)d_ws + tBytes);
    }
    unsigned short* Tsent = T + (size_t)MTOT * ODIM;

    prep_w    <<<128,        256, 0, stream>>>(W, Bcat, Tsent);
    gemm_mfma <<<MTOT / 64,  256, 0, stream>>>(x, Bcat, bias, U, T);
    gather_max<<<MTOT / 16,  256, 0, stream>>>(idx, U, T, out);
}